// Round 2
// baseline (210.049 us; speedup 1.0000x reference)
//
#include <hip/hip_runtime.h>
#include <hip/hip_bf16.h>

// ---------------------------------------------------------------------------
// Binary CNN forward (eval):
//  conv3x3(sign(x), sign(W1)) + b1 -> maxpool2x2 -> BN -> hardtanh -> sign
//  -> xnor-popcount GEMM vs sign(W2) + b2 -> BN -> hardtanh
//  -> fp32 GEMM vs W3 + b3 -> log_softmax
// ---------------------------------------------------------------------------

#define EPS 1e-5f

// ---------- Stage 1: conv + pool + BN sign -> packed bits (98 u64 / image) --
__global__ __launch_bounds__(256) void conv_pool_bin(
    const float* __restrict__ x, const float* __restrict__ W1,
    const float* __restrict__ b1, const float* __restrict__ g1,
    const float* __restrict__ be1, const float* __restrict__ m1,
    const float* __restrict__ v1, unsigned long long* __restrict__ Apack) {
  __shared__ float sx[30][30];   // zero-padded binarized image
  __shared__ float wsg[32][9];   // sign(W1)
  __shared__ float cA[32], cB[32];

  const int t = threadIdx.x;
  const int b = blockIdx.x;

  // zero the whole padded tile (border stays 0 = conv zero-padding)
  for (int i = t; i < 900; i += 256) ((float*)sx)[i] = 0.f;
  __syncthreads();
  const float* xb = x + b * 784;
  for (int p = t; p < 784; p += 256) {
    float v = xb[p];
    sx[p / 28 + 1][p % 28 + 1] = (v >= 0.f) ? 1.f : -1.f;
  }
  // 288 entries, 256 threads -> strided loop (bug fix from R1)
  for (int i = t; i < 288; i += 256) wsg[i / 9][i % 9] = (W1[i] >= 0.f) ? 1.f : -1.f;
  if (t < 32) {
    float sc = g1[t] * rsqrtf(v1[t] + EPS);
    cA[t] = sc;
    cB[t] = sc * (b1[t] - m1[t]) + be1[t];  // pred = sc*maxconv + cB >= 0
  }
  __syncthreads();

  const int lane = t & 63, wave = t >> 6;
  for (int it = 0; it < 25; it++) {
    int f = it * 256 + t;  // flatten index c*196 + h*14 + w
    bool pred = false;
    if (f < 6272) {
      int c = f / 196;
      int pos = f - c * 196;
      int h = pos / 14, w = pos - h * 14;
      int i0 = 2 * h, j0 = 2 * w;
      float p[4][4];
#pragma unroll
      for (int ii = 0; ii < 4; ii++)
#pragma unroll
        for (int jj = 0; jj < 4; jj++) p[ii][jj] = sx[i0 + ii][j0 + jj];
      float mx = -1e30f;
#pragma unroll
      for (int di = 0; di < 2; di++)
#pragma unroll
        for (int dj = 0; dj < 2; dj++) {
          float acc = 0.f;
#pragma unroll
          for (int kh = 0; kh < 3; kh++)
#pragma unroll
            for (int kw = 0; kw < 3; kw++)
              acc += p[di + kh][dj + kw] * wsg[c][kh * 3 + kw];
          mx = fmaxf(mx, acc);
        }
      pred = (cA[c] * mx + cB[c]) >= 0.f;
    }
    unsigned long long word = __ballot(pred);
    int wi = it * 4 + wave;
    if (lane == 0 && wi < 98) Apack[(long)b * 98 + wi] = word;
  }
}

// ---------- Pack sign(W2): 2048 rows x 98 u64 ------------------------------
__global__ __launch_bounds__(256) void pack_w2(
    const float* __restrict__ W2, unsigned long long* __restrict__ Bpack) {
  const int row = blockIdx.x;
  const int t = threadIdx.x, lane = t & 63, wave = t >> 6;
  const float* wr = W2 + (long)row * 6272;
  for (int it = 0; it < 25; it++) {
    int f = it * 256 + t;
    bool pred = (f < 6272) ? (wr[f] >= 0.f) : false;
    unsigned long long word = __ballot(pred);
    int wi = it * 4 + wave;
    if (lane == 0 && wi < 98) Bpack[(long)row * 98 + wi] = word;
  }
}

// ---------- XNOR-popcount GEMM 4096x2048 (K = 98 u64 words) + BN2 + clip ----
#define BKW 49
__global__ __launch_bounds__(256) void bin_gemm(
    const unsigned long long* __restrict__ Apack,
    const unsigned long long* __restrict__ Bpack,
    const float* __restrict__ b2, const float* __restrict__ g2,
    const float* __restrict__ be2, const float* __restrict__ m2,
    const float* __restrict__ v2, float* __restrict__ z) {
  __shared__ unsigned long long As[64 * BKW];
  __shared__ unsigned long long Bs[64 * BKW];
  const int t = threadIdx.x;
  const int tx = t & 15, ty = t >> 4;
  const int tileM = blockIdx.y * 64, tileN = blockIdx.x * 64;

  int acc[4][4] = {};
  for (int ko = 0; ko < 98; ko += BKW) {
    for (int idx = t; idx < 64 * BKW; idx += 256) {
      int r = idx / BKW, k = idx - r * BKW;
      As[idx] = Apack[(long)(tileM + r) * 98 + ko + k];
      Bs[idx] = Bpack[(long)(tileN + r) * 98 + ko + k];
    }
    __syncthreads();
    for (int k = 0; k < BKW; k++) {
      unsigned long long a[4], bb[4];
#pragma unroll
      for (int i = 0; i < 4; i++) a[i] = As[(ty + 16 * i) * BKW + k];
#pragma unroll
      for (int j = 0; j < 4; j++) bb[j] = Bs[(tx + 16 * j) * BKW + k];
#pragma unroll
      for (int i = 0; i < 4; i++)
#pragma unroll
        for (int j = 0; j < 4; j++) acc[i][j] += __popcll(a[i] ^ bb[j]);
    }
    __syncthreads();
  }

#pragma unroll
  for (int j = 0; j < 4; j++) {
    int col = tileN + tx + 16 * j;
    float bias = b2[col];
    float sc = g2[col] * rsqrtf(v2[col] + EPS);
    float mm = m2[col], bb2 = be2[col];
#pragma unroll
    for (int i = 0; i < 4; i++) {
      int row = tileM + ty + 16 * i;
      float dot = (float)(6272 - 2 * acc[i][j]);
      float bn = sc * (dot + bias - mm) + bb2;
      bn = fminf(1.f, fmaxf(-1.f, bn));
      z[(long)row * 2048 + col] = bn;
    }
  }
}

// ---------- Final fp32 linear (10 x 2048) + log_softmax --------------------
// W3 is only 80 KB total and reused by every block -> read from global (L2).
__global__ __launch_bounds__(256) void final_k(
    const float* __restrict__ z, const float* __restrict__ W3,
    const float* __restrict__ b3, float* __restrict__ out) {
  __shared__ float logits_s[4][10];
  const int t = threadIdx.x;
  const int wave = t >> 6, lane = t & 63;
  const int row = blockIdx.x * 4 + wave;
  float zr[32];
#pragma unroll
  for (int i = 0; i < 32; i++) zr[i] = z[(long)row * 2048 + lane + 64 * i];
  for (int cls = 0; cls < 10; cls++) {
    const float* w3r = W3 + cls * 2048;
    float acc = 0.f;
#pragma unroll
    for (int i = 0; i < 32; i++) acc += zr[i] * w3r[lane + 64 * i];
#pragma unroll
    for (int off = 32; off; off >>= 1) acc += __shfl_xor(acc, off);
    if (lane == 0) logits_s[wave][cls] = acc + b3[cls];
  }
  __syncthreads();
  if (lane < 10) {
    float v = logits_s[wave][lane];
    float m = logits_s[wave][0];
#pragma unroll
    for (int j = 1; j < 10; j++) m = fmaxf(m, logits_s[wave][j]);
    float s = 0.f;
#pragma unroll
    for (int j = 0; j < 10; j++) s += expf(logits_s[wave][j] - m);
    out[(long)row * 10 + lane] = v - m - logf(s);
  }
}

// ---------------------------------------------------------------------------
extern "C" void kernel_launch(void* const* d_in, const int* in_sizes, int n_in,
                              void* d_out, int out_size, void* d_ws, size_t ws_size,
                              hipStream_t stream) {
  const float* x   = (const float*)d_in[0];
  const float* W1  = (const float*)d_in[1];
  const float* b1  = (const float*)d_in[2];
  const float* g1  = (const float*)d_in[3];
  const float* be1 = (const float*)d_in[4];
  const float* m1  = (const float*)d_in[5];
  const float* v1  = (const float*)d_in[6];
  const float* W2  = (const float*)d_in[7];
  const float* b2  = (const float*)d_in[8];
  const float* g2  = (const float*)d_in[9];
  const float* be2 = (const float*)d_in[10];
  const float* m2  = (const float*)d_in[11];
  const float* v2  = (const float*)d_in[12];
  const float* W3  = (const float*)d_in[13];
  const float* b3  = (const float*)d_in[14];

  char* ws = (char*)d_ws;
  unsigned long long* Apack = (unsigned long long*)ws;                    // 4096*98*8 = 3,211,264 B
  unsigned long long* Bpack = (unsigned long long*)(ws + 3211264);        // 2048*98*8 = 1,605,632 B
  float* z = (float*)(ws + 3211264 + 1605632);                            // 4096*2048*4 = 33,554,432 B

  conv_pool_bin<<<4096, 256, 0, stream>>>(x, W1, b1, g1, be1, m1, v1, Apack);
  pack_w2<<<2048, 256, 0, stream>>>(W2, Bpack);
  bin_gemm<<<dim3(32, 64), 256, 0, stream>>>(Apack, Bpack, b2, g2, be2, m2, v2, z);
  final_k<<<1024, 256, 0, stream>>>(z, W3, b3, (float*)d_out);
}